// Round 5
// baseline (508.332 us; speedup 1.0000x reference)
//
#include <hip/hip_runtime.h>

// SIREN INR MLP — numpy-float32 emulation, packed-fp32, SGPR-pair weights.
// R4: 484 us, VALU-issue-bound; ~33% over the instruction-cycle floor.
// Suspect: VOP3P has no literal/broadcast-free splat, so splat2(weight) costs
// v_mov pairs. R5: pre-pass duplicates every weight to {w,w} (8B) in d_ws; the
// main kernel loads it as a wave-uniform double -> even SGPR pair -> direct
// scalar operand of v_pk_*_f32 (1 SGPR read per VALU instr: legal). Arithmetic
// is bit-identical to R4 (same ops, same order, contract off).

typedef float v2f __attribute__((ext_vector_type(2)));

static constexpr int PW = 921;

__device__ __forceinline__ v2f fma2(v2f a, v2f b, v2f c) {
    return __builtin_elementwise_fma(a, b, c);
}
__device__ __forceinline__ v2f splat2(float x) { v2f r; r.x = x; r.y = x; return r; }

template<bool PAIRED>
__device__ __forceinline__ v2f getw(const float* __restrict__ w,
                                    const double* __restrict__ wd, int k) {
    if constexpr (PAIRED) {
        return __builtin_bit_cast(v2f, wd[k]);   // uniform -> s_load pair {w,w}
    } else {
        return splat2(w[k]);
    }
}

// numpy SIMD f32 sin, 2 points packed (identical arithmetic to R3/R4).
__device__ __forceinline__ v2f np_sinf2(v2f x) {
#pragma clang fp contract(off)
    v2f t = x * splat2(0x1.45f306p-1f);
    v2f qf; qf.x = __builtin_rintf(t.x); qf.y = __builtin_rintf(t.y);
    const int qx = (int)qf.x, qy = (int)qf.y;
    v2f r = fma2(qf, splat2(-0x1.921fb0p+0f), x);
    r = fma2(qf, splat2(-0x1.5110b4p-22f), r);
    r = fma2(qf, splat2(-0x1.846988p-48f), r);
    v2f r2 = r * r;
    v2f ys = fma2(splat2(0x1.5e9e9cp-19f), r2, splat2(-0x1.a06bbap-13f));
    ys = fma2(ys, r2, splat2(0x1.11119ap-7f));
    ys = fma2(ys, r2, splat2(-0x1.555556p-3f));
    ys = ys * r2;
    ys = fma2(ys, r, r);
    v2f yc = fma2(splat2(0x1.98e616p-16f), r2, splat2(-0x1.6c06dcp-10f));
    yc = fma2(yc, r2, splat2(0x1.55553cp-5f));
    yc = fma2(yc, r2, splat2(-0.5f));
    yc = fma2(yc, r2, splat2(1.0f));
    v2f res;
    res.x = (qx & 1) ? yc.x : ys.x;
    res.y = (qy & 1) ? yc.y : ys.y;
    res.x = (qx & 2) ? -res.x : res.x;
    res.y = (qy & 2) ? -res.y : res.y;
    return res;
}

// numpy einsum contig_contig_outstride0_two accumulation tree (unchanged).
template<bool PAIRED>
__device__ __forceinline__ v2f np_dot20_2(const float* __restrict__ w,
                                          const double* __restrict__ wd,
                                          int off, const v2f* h) {
#pragma clang fp contract(off)
    v2f s[4];
#pragma unroll
    for (int j = 0; j < 4; ++j) {
        v2f p0  = h[j]      * getw<PAIRED>(w, wd, off + j);
        v2f p4  = h[4 + j]  * getw<PAIRED>(w, wd, off + 4 + j);
        v2f p8  = h[8 + j]  * getw<PAIRED>(w, wd, off + 8 + j);
        v2f p12 = h[12 + j] * getw<PAIRED>(w, wd, off + 12 + j);
        v2f p16 = h[16 + j] * getw<PAIRED>(w, wd, off + 16 + j);
        v2f t = p8 + p12;
        t = p4 + t;
        t = p0 + t;
        s[j] = p16 + t;
    }
    return (s[0] + s[1]) + (s[2] + s[3]);
}

template<bool PAIRED>
__global__ void __launch_bounds__(256)
siren_mlp(const float* __restrict__ coords,
          const float* __restrict__ weights,
          const double* __restrict__ wdup,
          float* __restrict__ out, int N)
{
#pragma clang fp contract(off)
    const int b = blockIdx.y;
    const float*  __restrict__ w  = weights + b * PW;        // wave-uniform
    const double* __restrict__ wd = wdup    + b * PW;        // wave-uniform pairs
    const int n0 = blockIdx.x * 512 + threadIdx.x;
    const int n1 = n0 + 256;
    const size_t base = (size_t)b * N;

    const float2* __restrict__ cp = (const float2*)coords;
    const float2 c0 = cp[base + n0];
    const float2 c1 = cp[base + n1];
    v2f X; X.x = c0.x; X.y = c1.x;
    v2f Y; Y.x = c0.y; Y.y = c1.y;

    v2f h[20], g[20];

    // ---- layer 0: 2 -> 20. (x*w0) + (y*w1), +b, *20 (no fma anywhere).
#pragma unroll
    for (int o = 0; o < 20; ++o) {
        v2f z = (X * getw<PAIRED>(w, wd, 2 * o)) + (Y * getw<PAIRED>(w, wd, 2 * o + 1));
        z = z + getw<PAIRED>(w, wd, 40 + o);
        h[o] = np_sinf2(splat2(20.0f) * z);
    }

    // ---- layer 1: 20 -> 20
#pragma unroll
    for (int o = 0; o < 20; ++o) {
        v2f z = np_dot20_2<PAIRED>(w, wd, 60 + 20 * o, h) + getw<PAIRED>(w, wd, 460 + o);
        g[o] = np_sinf2(splat2(20.0f) * z);
    }

    // ---- layer 2: 20 -> 20
#pragma unroll
    for (int o = 0; o < 20; ++o) {
        v2f z = np_dot20_2<PAIRED>(w, wd, 480 + 20 * o, g) + getw<PAIRED>(w, wd, 880 + o);
        h[o] = np_sinf2(splat2(20.0f) * z);
    }

    // ---- layer 3: 20 -> 1, clip[0,1]
    {
        v2f z = np_dot20_2<PAIRED>(w, wd, 900, h) + getw<PAIRED>(w, wd, 920);
        z.x = fminf(fmaxf(z.x, 0.0f), 1.0f);
        z.y = fminf(fmaxf(z.y, 0.0f), 1.0f);
        out[base + n0] = z.x;
        out[base + n1] = z.y;
    }
}

// Pre-pass: duplicate each weight into an 8-byte {w,w} pair in workspace.
__global__ void __launch_bounds__(256)
dup_weights(const float* __restrict__ w, double* __restrict__ wd, int total)
{
    int i = blockIdx.x * 256 + threadIdx.x;
    if (i < total) {
        float v = w[i];
        v2f p; p.x = v; p.y = v;
        wd[i] = __builtin_bit_cast(double, p);
    }
}

extern "C" void kernel_launch(void* const* d_in, const int* in_sizes, int n_in,
                              void* d_out, int out_size, void* d_ws, size_t ws_size,
                              hipStream_t stream) {
    const float* coords  = (const float*)d_in[0];
    const float* weights = (const float*)d_in[1];
    float* out = (float*)d_out;

    const int B = in_sizes[1] / PW;            // 128
    const int N = in_sizes[0] / (2 * B);       // 65536
    const int total = B * PW;

    dim3 grid(N / 512, B);
    const size_t need = (size_t)total * sizeof(double);

    if (ws_size >= need) {
        double* wd = (double*)d_ws;
        dup_weights<<<(total + 255) / 256, 256, 0, stream>>>(weights, wd, total);
        siren_mlp<true><<<grid, dim3(256), 0, stream>>>(coords, weights, wd, out, N);
    } else {
        siren_mlp<false><<<grid, dim3(256), 0, stream>>>(coords, weights, nullptr, out, N);
    }
}

// Round 7
// 442.846 us; speedup vs baseline: 1.1479x; 1.1479x over previous
//
#include <hip/hip_runtime.h>

// SIREN INR MLP — numpy-float32 emulation, packed-fp32.
// R4 (PASS, 484us) -> R6 changed magic-rint AND fma-dots together -> absmax 1.0.
// R7 = clean bisection: R4 verbatim + ONLY fma-chained L2/L3 dots.
//   - L0/L1 keep the exact numpy einsum tree + separate mul/add roundings
//     (their rounding differences amplify 1e3-1e4x through two sin layers).
//   - L2/L3 reassociation passes through at most one sin => bounded ~3e-3.
//   - sin = R4's rintf-based numpy SIMD algorithm, untouched.

typedef float v2f __attribute__((ext_vector_type(2)));

static constexpr int PW = 921;

__device__ __forceinline__ v2f fma2(v2f a, v2f b, v2f c) {
    return __builtin_elementwise_fma(a, b, c);
}
__device__ __forceinline__ v2f splat2(float x) { v2f r; r.x = x; r.y = x; return r; }

// numpy SIMD f32 sin, 2 points packed — R4 verbatim (PASSED config).
__device__ __forceinline__ v2f np_sinf2(v2f x) {
#pragma clang fp contract(off)
    v2f t = x * splat2(0x1.45f306p-1f);
    v2f qf; qf.x = __builtin_rintf(t.x); qf.y = __builtin_rintf(t.y);
    const int qx = (int)qf.x, qy = (int)qf.y;
    v2f r = fma2(qf, splat2(-0x1.921fb0p+0f), x);
    r = fma2(qf, splat2(-0x1.5110b4p-22f), r);
    r = fma2(qf, splat2(-0x1.846988p-48f), r);
    v2f r2 = r * r;
    v2f ys = fma2(splat2(0x1.5e9e9cp-19f), r2, splat2(-0x1.a06bbap-13f));
    ys = fma2(ys, r2, splat2(0x1.11119ap-7f));
    ys = fma2(ys, r2, splat2(-0x1.555556p-3f));
    ys = ys * r2;
    ys = fma2(ys, r, r);
    v2f yc = fma2(splat2(0x1.98e616p-16f), r2, splat2(-0x1.6c06dcp-10f));
    yc = fma2(yc, r2, splat2(0x1.55553cp-5f));
    yc = fma2(yc, r2, splat2(-0.5f));
    yc = fma2(yc, r2, splat2(1.0f));
    v2f res;
    res.x = (qx & 1) ? yc.x : ys.x;
    res.y = (qy & 1) ? yc.y : ys.y;
    res.x = (qx & 2) ? -res.x : res.x;
    res.y = (qy & 2) ? -res.y : res.y;
    return res;
}

// numpy einsum contig_contig_outstride0_two tree (exact) — L1.
__device__ __forceinline__ v2f np_dot20_2(const float* __restrict__ w,
                                          const v2f* h) {
#pragma clang fp contract(off)
    v2f s[4];
#pragma unroll
    for (int j = 0; j < 4; ++j) {
        v2f p0  = h[j]      * splat2(w[j]);
        v2f p4  = h[4 + j]  * splat2(w[4 + j]);
        v2f p8  = h[8 + j]  * splat2(w[8 + j]);
        v2f p12 = h[12 + j] * splat2(w[12 + j]);
        v2f p16 = h[16 + j] * splat2(w[16 + j]);
        v2f t = p8 + p12;
        t = p4 + t;
        t = p0 + t;
        s[j] = p16 + t;
    }
    return (s[0] + s[1]) + (s[2] + s[3]);
}

// FMA-chain dot (bias-initialized) — L2/L3 only (bounded amplification).
__device__ __forceinline__ v2f fma_dot20(const float* __restrict__ w,
                                         const v2f* h, float bias) {
#pragma clang fp contract(off)
    v2f acc = splat2(bias);
#pragma unroll
    for (int i = 0; i < 20; ++i)
        acc = fma2(splat2(w[i]), h[i], acc);
    return acc;
}

__global__ void __launch_bounds__(256)
siren_mlp(const float* __restrict__ coords,
          const float* __restrict__ weights,
          float* __restrict__ out, int N)
{
#pragma clang fp contract(off)
    const int b = blockIdx.y;
    const float* __restrict__ w = weights + b * PW;  // wave-uniform -> s_load
    const int n0 = blockIdx.x * 512 + threadIdx.x;
    const int n1 = n0 + 256;
    const size_t base = (size_t)b * N;

    const float2* __restrict__ cp = (const float2*)coords;
    const float2 c0 = cp[base + n0];
    const float2 c1 = cp[base + n1];
    v2f X; X.x = c0.x; X.y = c1.x;
    v2f Y; Y.x = c0.y; Y.y = c1.y;

    v2f h[20], g[20];

    // ---- layer 0: 2 -> 20. (x*w0)+(y*w1), +b, *20 — numpy-exact, no fma.
#pragma unroll
    for (int o = 0; o < 20; ++o) {
        v2f z = (X * splat2(w[2 * o])) + (Y * splat2(w[2 * o + 1]));
        z = z + splat2(w[40 + o]);
        h[o] = np_sinf2(splat2(20.0f) * z);
    }

    // ---- layer 1: 20 -> 20 — numpy-exact tree.
#pragma unroll
    for (int o = 0; o < 20; ++o) {
        v2f z = np_dot20_2(w + 60 + 20 * o, h) + splat2(w[460 + o]);
        g[o] = np_sinf2(splat2(20.0f) * z);
    }

    // ---- layer 2: 20 -> 20 — fma chain.
#pragma unroll
    for (int o = 0; o < 20; ++o) {
        v2f z = fma_dot20(w + 480 + 20 * o, g, w[880 + o]);
        h[o] = np_sinf2(splat2(20.0f) * z);
    }

    // ---- layer 3: 20 -> 1, clip[0,1] — fma chain.
    {
        v2f z = fma_dot20(w + 900, h, w[920]);
        z.x = fminf(fmaxf(z.x, 0.0f), 1.0f);
        z.y = fminf(fmaxf(z.y, 0.0f), 1.0f);
        out[base + n0] = z.x;
        out[base + n1] = z.y;
    }
}

extern "C" void kernel_launch(void* const* d_in, const int* in_sizes, int n_in,
                              void* d_out, int out_size, void* d_ws, size_t ws_size,
                              hipStream_t stream) {
    const float* coords  = (const float*)d_in[0];
    const float* weights = (const float*)d_in[1];
    float* out = (float*)d_out;

    const int B = in_sizes[1] / PW;            // 128
    const int N = in_sizes[0] / (2 * B);       // 65536

    dim3 grid(N / 512, B);
    siren_mlp<<<grid, dim3(256), 0, stream>>>(coords, weights, out, N);
}